// Round 9
// baseline (2941.667 us; speedup 1.0000x reference)
//
#include <hip/hip_runtime.h>
#include <cstdint>
#include <cstddef>

// Problem constants
#define B_  4096
#define H_  300
#define T_  43
#define NC_ 80
#define HP  320      // padded hidden/input dim (300 -> 320)
#define ND  1280     // padded 4H per direction
#define NDD 2560     // both directions
#define KC  640      // concatenated K: [x_t (320) ; h_prev (320)]
#define TR  304      // hs per-t row length in f16 (300 + 4 zero pad, 16B aligned)
#define SB2 (T_ * TR) // hs per-(d,b) stride in f16 = 13072
#define BT  32       // batch tile per block

// LDS layout (bytes).
//  A-slab pipeline: 4 buffers x 16 KB (256 rows x 32 k f16, chunk-linear
//  [lq][row] so ds_read_b128 is 2-way-bank (free)).
//  h rows padded to 328 f16 (656 B -> 2-way bank spread).
#define HROW 328
#define A_OFF    0
#define NBUF     4
#define SLABB    16384
#define H0_OFF   (A_OFF + NBUF * SLABB)       // 65536
#define H1_OFF   (H0_OFF + BT * HROW * 2)     // 86528
#define C_OFF    (H1_OFF + BT * HROW * 2)     // 107520 (c[320][33] f32)
#define BIAS_OFF (C_OFF + 320 * 33 * 4)       // 149760 (bias[1280] f32)
#define LDS_TOTAL (BIAS_OFF + 1280 * 4)       // 154880  (<= 160 KiB)

typedef _Float16 f16;
typedef _Float16 half8 __attribute__((ext_vector_type(8)));
typedef _Float16 half4 __attribute__((ext_vector_type(4)));
typedef float    f32x4 __attribute__((ext_vector_type(4)));

__device__ __forceinline__ void gl_lds16(const void* g, void* l) {
  __builtin_amdgcn_global_load_lds(
      (const __attribute__((address_space(1))) void*)g,
      (__attribute__((address_space(3))) void*)l, 16, 0, 0);
}
__device__ __forceinline__ float sigmoid_(float x) {
  return 1.f / (1.f + __expf(-x));
}
__device__ __forceinline__ float tanh_fast(float x) {
  x = fminf(fmaxf(x, -15.f), 15.f);
  float e = __expf(2.f * x);
  return (e - 1.f) / (e + 1.f);
}

// ---------------------------------------------------------------------------
// Weight packing, concatenated-K layout. Row index = d*1280 + 4*jh + g
// (gate-interleaved, order i,f,g,o). Wcat[2560][640]: cols 0..319 = Wih row
// (k < 300 real), cols 320..639 = Whh row. bias[2560] = b_ih + b_hh.
// ---------------------------------------------------------------------------
__global__ void prep_weights(const float* __restrict__ w_ih,
                             const float* __restrict__ w_hh,
                             const float* __restrict__ b_ih,
                             const float* __restrict__ b_hh,
                             f16* __restrict__ Wcat, float* __restrict__ bias) {
  int idx = blockIdx.x * 256 + threadIdx.x;
  const int total = NDD * KC;
  if (idx < total) {
    int row = idx / KC, k = idx % KC;
    int d = row / ND, n = row % ND;
    int jh = n >> 2, g = n & 3;
    int which = (k >= HP);           // 0 = Wih part, 1 = Whh part
    int kk = which ? (k - HP) : k;
    float v = 0.f;
    if (jh < H_ && kk < H_) {
      const float* W = which ? w_hh : w_ih;
      v = W[((size_t)d * 4 * H_ + g * H_ + jh) * H_ + kk];
    }
    Wcat[(size_t)row * KC + k] = (f16)v;
  }
  if (idx < NDD) {
    int d = idx / ND, n = idx % ND;
    int jh = n >> 2, g = n & 3;
    float v = 0.f;
    if (jh < H_)
      v = b_ih[d * 4 * H_ + g * H_ + jh] + b_hh[d * 4 * H_ + g * H_ + jh];
    bias[idx] = v;
  }
}

// ---------------------------------------------------------------------------
// x [B,H,T] fp32 -> xT[t*B+b][k] f16, k padded to 320 with zeros.
// ---------------------------------------------------------------------------
__global__ void prep_xT(const float* __restrict__ x, f16* __restrict__ xT) {
  __shared__ float tile[64][44];
  int b = blockIdx.x, ch = blockIdx.y;
  int h0 = ch * 64;
  for (int idx = threadIdx.x; idx < 64 * T_; idx += 256) {
    int hh = idx / T_, t = idx % T_;
    float v = 0.f;
    if (h0 + hh < H_) v = x[((size_t)b * H_ + h0 + hh) * T_ + t];
    tile[hh][t] = v;
  }
  __syncthreads();
  for (int idx = threadIdx.x; idx < 64 * T_; idx += 256) {
    int t = idx / 64, hh = idx % 64;
    xT[((size_t)t * B_ + b) * HP + h0 + hh] = (f16)tile[hh][t];
  }
}

// ---------------------------------------------------------------------------
// Batch-sliced persistent LSTM, DMA-pipelined weights.
// One block owns (direction d, 32 batch rows) for ALL 43 timesteps; no
// inter-block dependency. h ping-pongs in LDS, c in LDS, bfx (B-fragments
// for all 20 K-steps) in registers (~190 VGPR total, no pressure).
// Weights: 100 slabs/step (5 M-chunks x 20 K-steps, 16 KB each) staged
// L2 -> LDS via global_load_lds into a 4-buffer rolling pipeline, 2 slabs
// ahead, counted  s_waitcnt vmcnt(8)  + raw s_barrier (never drains to 0).
// DMA consumes no VGPRs -> the register allocator cannot collapse the
// pipeline (which is what killed rounds 3-6's register prefetch designs).
// grid flat 256 = 1 block/CU; xcd=id&7 groups directions per-XCD so each
// XCD caches only its 1.64 MB weight set in L2.
// ---------------------------------------------------------------------------
__global__ __launch_bounds__(256, 1) void lstm_all(
    const f16* __restrict__ xT,     // [T][B][320]
    const f16* __restrict__ Wcat,   // [2560][640]
    const float* __restrict__ bias, // [2560]
    f16* __restrict__ hs) {         // [2][B][43][304]
  extern __shared__ __attribute__((aligned(16))) char smem[];
  f16* h0s = (f16*)(smem + H0_OFF);
  f16* h1s = (f16*)(smem + H1_OFF);
  float* cls = (float*)(smem + C_OFF);
  float* bl = (float*)(smem + BIAS_OFF);

  const int tid = threadIdx.x;
  const int wave = tid >> 6, lane = tid & 63;
  const int lr = lane & 15, lq = lane >> 4;
  const int kq = lq << 3;

  // XCD-grouped decode: all blocks on one XCD share a direction.
  const int id = blockIdx.x;
  const int xcd = id & 7, slot = id >> 3;
  const int d = xcd >> 2;
  const int bt = (xcd & 3) * 32 + slot;   // 0..127

  // ---- init: bias -> LDS, zero c, zero h0 ----
  for (int i = tid; i < 1280; i += 256) bl[i] = bias[d * ND + i];
  for (int i = tid; i < 320 * 33; i += 256) cls[i] = 0.f;
  for (int i = tid; i < BT * HROW; i += 256) h0s[i] = (f16)0.f;

  // ---- weight staging map ----
  // Slab (m,kt) = W rows [m*256, m*256+256) x cols [kt*32, kt*32+32).
  // LDS chunk layout: chunk q = lq_s*256 + row_s  (16B chunks), linear.
  // Per wave call c (0..3): chunk q = (wave*4+c)*64 + lane.
  const f16* Wd = Wcat + (size_t)d * ND * KC;
  size_t soff[4];   // global f16 offset of this thread's chunk, per call
#pragma unroll
  for (int c = 0; c < 4; ++c) {
    int q = (wave * 4 + c) * 64 + lane;
    int row_s = q & 255, lq_s = q >> 8;
    soff[c] = (size_t)row_s * KC + lq_s * 8;
  }
  const int dbase = (wave * 4) * 1024;  // this wave's LDS byte base in a slab

#define STAGE(M2, KT2, BUF)                                                  \
  {                                                                          \
    const f16* wsrc = Wd + (size_t)(M2) * (256 * KC) + (KT2) * 32;           \
    char* dst = smem + A_OFF + (BUF) * SLABB + dbase;                        \
    gl_lds16(wsrc + soff[0], dst);                                           \
    gl_lds16(wsrc + soff[1], dst + 1024);                                    \
    gl_lds16(wsrc + soff[2], dst + 2048);                                    \
    gl_lds16(wsrc + soff[3], dst + 3072);                                    \
  }

  // prologue: stage slabs 0 (m=0,kt=0) and 1 (m=0,kt=1)
  STAGE(0, 0, 0)
  STAGE(0, 1, 1)
  __syncthreads();  // also covers LDS init; drains vmcnt once (prologue only)

  // A-fragment LDS read base (f16 index): chunk (lq*256 + wave*64 + i*16+lr)
  const int abase = (lq * 256 + wave * 64 + lr) * 8;  // + i*128 per tile

  for (int t = 0; t < T_; ++t) {
    const f16* hcur = (t & 1) ? h1s : h0s;
    f16* hnxt = (t & 1) ? h0s : h1s;

    // ---- B-fragments for ALL 20 K-steps (chunk-invariant): 160 VGPRs ----
    // x-part straight from global (xT slice is tiny + L2/HBM-streamed);
    // h-part from LDS ping-pong buffer.
    half8 bfx[20][2];
    {
      const f16* xb = xT + ((size_t)t * B_ + bt * BT) * HP;
#pragma unroll
      for (int K = 0; K < 10; ++K)
#pragma unroll
        for (int j = 0; j < 2; j++)
          bfx[K][j] = *(const half8*)(xb + (j * 16 + lr) * HP + K * 32 + kq);
#pragma unroll
      for (int K = 10; K < 20; ++K)
#pragma unroll
        for (int j = 0; j < 2; j++)
          bfx[K][j] =
              *(const half8*)(hcur + (j * 16 + lr) * HROW + (K - 10) * 32 + kq);
    }

    for (int m = 0; m < 5; ++m) {
      f32x4 acc[4][2];
#pragma unroll
      for (int i = 0; i < 4; i++)
#pragma unroll
        for (int j = 0; j < 2; j++) acc[i][j] = (f32x4){0.f, 0.f, 0.f, 0.f};

#pragma unroll
      for (int kt = 0; kt < 20; ++kt) {
        // stage slab g+2 (g = m*20+kt); wraps to next timestep's slabs 0/1
        // (weights are t-invariant, so the pipeline free-runs across t).
        {
          int m2, kt2;
          if (kt < 18) { m2 = m; kt2 = kt + 2; }
          else         { m2 = (m == 4) ? 0 : m + 1; kt2 = kt - 18; }
          const int buf2 = (m * 20 + kt + 2) & 3;
          STAGE(m2, kt2, buf2)
        }
        // wait for slab g (8 newest vmem ops = the 2 in-flight slabs; any
        // interleaved x-loads/stores only cause a harmless over-wait)
        asm volatile("s_waitcnt vmcnt(8)" ::: "memory");
        __builtin_amdgcn_s_barrier();

        const int buf = (m * 20 + kt) & 3;
        const f16* Af = (const f16*)(smem + A_OFF + buf * SLABB);
        half8 af[4];
#pragma unroll
        for (int i = 0; i < 4; i++) af[i] = *(const half8*)(Af + abase + i * 128);
#pragma unroll
        for (int i = 0; i < 4; i++)
#pragma unroll
          for (int j = 0; j < 2; j++)
            acc[i][j] = __builtin_amdgcn_mfma_f32_16x16x32_f16(
                af[i], bfx[kt][j], acc[i][j], 0, 0, 0);
      }

      // ---- gate epilogue for this chunk: c (LDS), h_new -> hnxt ----
#pragma unroll
      for (int i = 0; i < 4; i++) {
        const int jh = m * 64 + wave * 16 + i * 4 + lq;  // 0..319
        const float4 b4 = *(const float4*)&bl[4 * jh];
#pragma unroll
        for (int j = 0; j < 2; j++) {
          const int b = j * 16 + lr;  // 0..31
          float* cp = &cls[jh * 33 + b];
          const float co = *cp;
          const float zi = acc[i][j][0] + b4.x;
          const float zf = acc[i][j][1] + b4.y;
          const float zg = acc[i][j][2] + b4.z;
          const float zo = acc[i][j][3] + b4.w;
          const float cn = sigmoid_(zf) * co + sigmoid_(zi) * tanh_fast(zg);
          *cp = cn;  // pad rows (jh>=300): zero weights/bias -> stays 0
          hnxt[b * HROW + jh] = (f16)(sigmoid_(zo) * tanh_fast(cn));
        }
      }
    }

    // t-end: make hnxt visible to all waves WITHOUT draining the DMA queue
    asm volatile("s_waitcnt lgkmcnt(0)" ::: "memory");
    __builtin_amdgcn_s_barrier();

    // ---- hs write-out: rows [b][304] contiguous from hnxt row b ----
    for (int idx = tid; idx < 32 * 38; idx += 256) {
      const int b = idx / 38, ch = idx % 38;  // 38 half8 chunks = 304 f16
      f16* dst = hs + ((size_t)d * B_ + bt * BT + b) * SB2 + t * TR;
      *(half8*)(dst + ch * 8) = *(const half8*)(hnxt + b * HROW + ch * 8);
    }
  }
#undef STAGE
}

// ---------------------------------------------------------------------------
// attn1: alpha[b][t] = softmax_t( sum_h tanh(hs0+hs1) * conv_w[h] ).
// Pure stream over hs; half4 loads (rows are 304-wide, zero-padded).
// ---------------------------------------------------------------------------
__global__ __launch_bounds__(256) void attn1(const f16* __restrict__ hs,
                                             const float* __restrict__ conv_w,
                                             float* __restrict__ alpha_g) {
  __shared__ float cw[TR];
  __shared__ float red[48];
  const int b = blockIdx.x, tid = threadIdx.x;
  const int wave = tid >> 6, lane = tid & 63;
  for (int k = tid; k < TR; k += 256) cw[k] = (k < H_) ? conv_w[k] : 0.f;
  __syncthreads();

  const half4* s0 = (const half4*)(hs + (size_t)b * SB2);
  const half4* s1 = (const half4*)(hs + (size_t)(B_ + b) * SB2);
  for (int t = wave; t < T_; t += 4) {
    const int base = t * (TR / 4);
    float p = 0.f;
    {
      half4 a = s0[base + lane], cc = s1[base + lane];
#pragma unroll
      for (int r = 0; r < 4; r++)
        p += tanh_fast((float)a[r] + (float)cc[r]) * cw[lane * 4 + r];
    }
    if (lane < 12) {
      half4 a = s0[base + 64 + lane], cc = s1[base + 64 + lane];
#pragma unroll
      for (int r = 0; r < 4; r++)
        p += tanh_fast((float)a[r] + (float)cc[r]) * cw[256 + lane * 4 + r];
    }
#pragma unroll
    for (int o = 32; o; o >>= 1) p += __shfl_down(p, o);
    if (lane == 0) red[t] = p;
  }
  __syncthreads();
  if (tid < 64) {
    float a = (tid < T_) ? red[tid] : -1e30f;
    float mx = a;
#pragma unroll
    for (int o = 32; o; o >>= 1) mx = fmaxf(mx, __shfl_xor(mx, o));
    float e = (tid < T_) ? __expf(a - mx) : 0.f;
    float s = e;
#pragma unroll
    for (int o = 32; o; o >>= 1) s += __shfl_xor(s, o);
    if (tid < T_) alpha_g[(size_t)b * 44 + tid] = e / s;
  }
}

// ---------------------------------------------------------------------------
// attn2: r[b][h] = sum_t hsum*alpha; hstar = tanh(r); logits; softmax.
// Thread-per-h accumulation, coalesced streaming.
// ---------------------------------------------------------------------------
__global__ __launch_bounds__(256) void attn2(const f16* __restrict__ hs,
                                             const float* __restrict__ alpha_g,
                                             const float* __restrict__ fc_w,
                                             const float* __restrict__ fc_b,
                                             float* __restrict__ out) {
  __shared__ float al[T_];
  __shared__ float hstar[TR];
  __shared__ float lg[NC_];
  const int b = blockIdx.x, tid = threadIdx.x;
  if (tid < T_) al[tid] = alpha_g[(size_t)b * 44 + tid];
  __syncthreads();

  const f16* s0 = hs + (size_t)b * SB2;
  const f16* s1 = hs + (size_t)(B_ + b) * SB2;
  float r0 = 0.f, r1 = 0.f;
  for (int t = 0; t < T_; t++) {
    const float a = al[t];
    r0 += ((float)s0[t * TR + tid] + (float)s1[t * TR + tid]) * a;
    if (tid < 48)
      r1 += ((float)s0[t * TR + 256 + tid] + (float)s1[t * TR + 256 + tid]) * a;
  }
  hstar[tid] = tanh_fast(r0);
  if (tid < 48) hstar[256 + tid] = tanh_fast(r1);
  __syncthreads();

  const int wave = tid >> 6, lane = tid & 63;
  for (int cls = wave; cls < NC_; cls += 4) {
    float p = 0.f;
    for (int k = lane; k < H_; k += 64) p += hstar[k] * fc_w[(size_t)cls * H_ + k];
#pragma unroll
    for (int o = 32; o; o >>= 1) p += __shfl_down(p, o);
    if (lane == 0) lg[cls] = p + fc_b[cls];
  }
  __syncthreads();
  if (tid < 64) {
    float a0 = (tid < 40) ? lg[tid] : -1e30f;
    float a1 = (tid < 40) ? lg[tid + 40] : -1e30f;
    float mx = fmaxf(a0, a1);
#pragma unroll
    for (int o = 32; o; o >>= 1) mx = fmaxf(mx, __shfl_xor(mx, o));
    float e0 = (tid < 40) ? __expf(a0 - mx) : 0.f;
    float e1 = (tid < 40) ? __expf(a1 - mx) : 0.f;
    float s = e0 + e1;
#pragma unroll
    for (int o = 32; o; o >>= 1) s += __shfl_xor(s, o);
    if (tid < 40) {
      out[(size_t)b * NC_ + tid] = e0 / s;
      out[(size_t)b * NC_ + tid + 40] = e1 / s;
    }
  }
}

// ---------------------------------------------------------------------------
extern "C" void kernel_launch(void* const* d_in, const int* in_sizes, int n_in,
                              void* d_out, int out_size, void* d_ws, size_t ws_size,
                              hipStream_t stream) {
  const float* x      = (const float*)d_in[0];
  const float* w_ih   = (const float*)d_in[1];
  const float* w_hh   = (const float*)d_in[2];
  const float* b_ih   = (const float*)d_in[3];
  const float* b_hh   = (const float*)d_in[4];
  const float* conv_w = (const float*)d_in[5];
  const float* fc_w   = (const float*)d_in[6];
  const float* fc_b   = (const float*)d_in[7];
  float* out = (float*)d_out;

  // Workspace carve (~331 MB)
  char* p = (char*)d_ws;
  f16* Wcat = (f16*)p;  p += (size_t)NDD * KC * sizeof(f16);        // 3.3 MB
  float* bias = (float*)p; p += (size_t)NDD * sizeof(float);
  p = (char*)(((uintptr_t)p + 255) & ~(uintptr_t)255);
  f16* xT = (f16*)p;    p += (size_t)T_ * B_ * HP * sizeof(f16);    // 112.7 MB
  f16* hs = (f16*)p;    p += (size_t)2 * B_ * SB2 * sizeof(f16);    // 214.2 MB
  float* alpha_g = (float*)p; p += (size_t)B_ * 44 * sizeof(float); // 0.72 MB

  prep_weights<<<(NDD * KC + 255) / 256, 256, 0, stream>>>(
      w_ih, w_hh, b_ih, b_hh, Wcat, bias);
  prep_xT<<<dim3(B_, 5), 256, 0, stream>>>(x, xT);

  lstm_all<<<256, 256, LDS_TOTAL, stream>>>(xT, Wcat, bias, hs);

  attn1<<<B_, 256, 0, stream>>>(hs, conv_w, alpha_g);
  attn2<<<B_, 256, 0, stream>>>(hs, alpha_g, fc_w, fc_b, out);
}

// Round 10
// 1809.463 us; speedup vs baseline: 1.6257x; 1.6257x over previous
//
#include <hip/hip_runtime.h>
#include <cstdint>
#include <cstddef>

// Problem constants
#define B_  4096
#define H_  300
#define T_  43
#define NC_ 80
#define HP  320      // padded hidden/input dim (300 -> 320)
#define ND  1280     // padded 4H per direction
#define NDD 2560     // both directions
#define KC  640      // concatenated K: [x_t (320) ; h_prev (320)]
#define TR  304      // hs per-t row length in f16 (300 + 4 zero pad, 16B aligned)
#define SB2 (T_ * TR) // hs per-(d,b) stride in f16 = 13072
#define BT  32       // batch tile per block

// LDS layout (bytes).
//  A-slab pipeline: 4 buffers x 16 KB, row-major [256 rows][32 k] f16
//  (m97 As-layout: row = 64 B, read addr = row*64 + kq*16).
//  h rows padded to 328 f16 (656 B -> 2-way bank spread).
#define HROW 328
#define A_OFF    0
#define NBUF     4
#define SLABB    16384
#define H0_OFF   (A_OFF + NBUF * SLABB)       // 65536
#define H1_OFF   (H0_OFF + BT * HROW * 2)     // 86528
#define C_OFF    (H1_OFF + BT * HROW * 2)     // 107520 (c[320][33] f32)
#define BIAS_OFF (C_OFF + 320 * 33 * 4)       // 149760 (bias[1280] f32)
#define LDS_TOTAL (BIAS_OFF + 1280 * 4)       // 154880  (<= 160 KiB)

typedef _Float16 f16;
typedef _Float16 half8 __attribute__((ext_vector_type(8)));
typedef _Float16 half4 __attribute__((ext_vector_type(4)));
typedef float    f32x4 __attribute__((ext_vector_type(4)));

__device__ __forceinline__ void gl_lds16(const void* g, void* l) {
  __builtin_amdgcn_global_load_lds(
      (const __attribute__((address_space(1))) void*)g,
      (__attribute__((address_space(3))) void*)l, 16, 0, 0);
}
__device__ __forceinline__ float sigmoid_(float x) {
  return 1.f / (1.f + __expf(-x));
}
__device__ __forceinline__ float tanh_fast(float x) {
  x = fminf(fmaxf(x, -15.f), 15.f);
  float e = __expf(2.f * x);
  return (e - 1.f) / (e + 1.f);
}

// ---------------------------------------------------------------------------
// Weight packing, concatenated-K layout. Row index = d*1280 + 4*jh + g
// (gate-interleaved, order i,f,g,o). Wcat[2560][640]: cols 0..319 = Wih row
// (k < 300 real), cols 320..639 = Whh row. bias[2560] = b_ih + b_hh.
// ---------------------------------------------------------------------------
__global__ void prep_weights(const float* __restrict__ w_ih,
                             const float* __restrict__ w_hh,
                             const float* __restrict__ b_ih,
                             const float* __restrict__ b_hh,
                             f16* __restrict__ Wcat, float* __restrict__ bias) {
  int idx = blockIdx.x * 256 + threadIdx.x;
  const int total = NDD * KC;
  if (idx < total) {
    int row = idx / KC, k = idx % KC;
    int d = row / ND, n = row % ND;
    int jh = n >> 2, g = n & 3;
    int which = (k >= HP);           // 0 = Wih part, 1 = Whh part
    int kk = which ? (k - HP) : k;
    float v = 0.f;
    if (jh < H_ && kk < H_) {
      const float* W = which ? w_hh : w_ih;
      v = W[((size_t)d * 4 * H_ + g * H_ + jh) * H_ + kk];
    }
    Wcat[(size_t)row * KC + k] = (f16)v;
  }
  if (idx < NDD) {
    int d = idx / ND, n = idx % ND;
    int jh = n >> 2, g = n & 3;
    float v = 0.f;
    if (jh < H_)
      v = b_ih[d * 4 * H_ + g * H_ + jh] + b_hh[d * 4 * H_ + g * H_ + jh];
    bias[idx] = v;
  }
}

// ---------------------------------------------------------------------------
// x [B,H,T] fp32 -> xT[t*B+b][k] f16, k padded to 320 with zeros.
// ---------------------------------------------------------------------------
__global__ void prep_xT(const float* __restrict__ x, f16* __restrict__ xT) {
  __shared__ float tile[64][44];
  int b = blockIdx.x, ch = blockIdx.y;
  int h0 = ch * 64;
  for (int idx = threadIdx.x; idx < 64 * T_; idx += 256) {
    int hh = idx / T_, t = idx % T_;
    float v = 0.f;
    if (h0 + hh < H_) v = x[((size_t)b * H_ + h0 + hh) * T_ + t];
    tile[hh][t] = v;
  }
  __syncthreads();
  for (int idx = threadIdx.x; idx < 64 * T_; idx += 256) {
    int t = idx / 64, hh = idx % 64;
    xT[((size_t)t * B_ + b) * HP + h0 + hh] = (f16)tile[hh][t];
  }
}

// ---------------------------------------------------------------------------
// Batch-sliced persistent LSTM, DMA-pipelined weights, COALESCED staging.
// One block owns (direction d, 32 batch rows) for ALL 43 timesteps; no
// inter-block dependency. h ping-pongs in LDS, c in LDS, bfx (B-fragments
// for all 20 K-steps) in registers.
// Weights: 100 slabs/step (5 M-chunks x 20 K-steps, 16 KB each) staged
// L2 -> LDS via global_load_lds into a 4-buffer rolling pipeline, 2 slabs
// ahead, counted  s_waitcnt vmcnt(8)  + raw s_barrier (never drains to 0).
// STAGING MAP (the round-10 fix): 4 lanes per W row -> each 4-lane group
// reads 64 B contiguous (full cacheline). Round 9's lane-per-row map read
// 16 B/lane at 1280 B stride = 25% cacheline use = 4x L2-BW waste, which
// was exactly the measured 4x gap (1430 cyc/slab vs 290 floor).
// grid flat 256 = 1 block/CU; xcd=id&7 groups directions per-XCD so each
// XCD caches only its 1.64 MB weight set in L2.
// ---------------------------------------------------------------------------
__global__ __launch_bounds__(256, 1) void lstm_all(
    const f16* __restrict__ xT,     // [T][B][320]
    const f16* __restrict__ Wcat,   // [2560][640]
    const float* __restrict__ bias, // [2560]
    f16* __restrict__ hs) {         // [2][B][43][304]
  extern __shared__ __attribute__((aligned(16))) char smem[];
  f16* h0s = (f16*)(smem + H0_OFF);
  f16* h1s = (f16*)(smem + H1_OFF);
  float* cls = (float*)(smem + C_OFF);
  float* bl = (float*)(smem + BIAS_OFF);

  const int tid = threadIdx.x;
  const int wave = tid >> 6, lane = tid & 63;
  const int lr = lane & 15, lq = lane >> 4;
  const int kq = lq << 3;

  // XCD-grouped decode: all blocks on one XCD share a direction.
  const int id = blockIdx.x;
  const int xcd = id & 7, slot = id >> 3;
  const int d = xcd >> 2;
  const int bt = (xcd & 3) * 32 + slot;   // 0..127

  // ---- init: bias -> LDS, zero c, zero h0 ----
  for (int i = tid; i < 1280; i += 256) bl[i] = bias[d * ND + i];
  for (int i = tid; i < 320 * 33; i += 256) cls[i] = 0.f;
  for (int i = tid; i < BT * HROW; i += 256) h0s[i] = (f16)0.f;

  // ---- weight staging map (coalesced) ----
  // Slab (m,kt) = W rows [m*256, +256) x cols [kt*32, +32). LDS row-major
  // [256][32]. Per wave call c (0..3): 16 rows (wave*4+c)*16 .. +16.
  // Lane: row-in-16 = lane>>2, colquad = lane&3 (8 f16 = 16 B).
  // -> each 4-lane group reads 64 B contiguous; LDS dest linear = lane*16 B
  //    lands row-major automatically.
  const f16* Wd = Wcat + (size_t)d * ND * KC;
  size_t soff[4];   // global f16 offset of this thread's chunk, per call
#pragma unroll
  for (int c = 0; c < 4; ++c) {
    int r0 = (wave * 4 + c) * 16 + (lane >> 2);
    soff[c] = (size_t)r0 * KC + (lane & 3) * 8;
  }
  const int dbase = (wave * 4) * 1024;  // this wave's LDS byte base in a slab

#define STAGE(M2, KT2, BUF)                                                  \
  {                                                                          \
    const f16* wsrc = Wd + (size_t)(M2) * (256 * KC) + (KT2) * 32;           \
    char* dst = smem + A_OFF + (BUF) * SLABB + dbase;                        \
    gl_lds16(wsrc + soff[0], dst);                                           \
    gl_lds16(wsrc + soff[1], dst + 1024);                                    \
    gl_lds16(wsrc + soff[2], dst + 2048);                                    \
    gl_lds16(wsrc + soff[3], dst + 3072);                                    \
  }

  // prologue: stage slabs 0 (m=0,kt=0) and 1 (m=0,kt=1)
  STAGE(0, 0, 0)
  STAGE(0, 1, 1)
  __syncthreads();  // also covers LDS init; drains vmcnt once (prologue only)

  // A-fragment read base (f16 index in slab): row (wave*64 + i*16 + lr),
  // k-quad lq -> (row)*32 + kq ; +i*512 per tile.
  const int abase = (wave * 64 + lr) * 32 + kq;

  for (int t = 0; t < T_; ++t) {
    const f16* hcur = (t & 1) ? h1s : h0s;
    f16* hnxt = (t & 1) ? h0s : h1s;

    // ---- B-fragments for ALL 20 K-steps (chunk-invariant): 160 VGPRs ----
    // x-part straight from global (xT slice is tiny + L2/HBM-streamed);
    // h-part from LDS ping-pong buffer.
    half8 bfx[20][2];
    {
      const f16* xb = xT + ((size_t)t * B_ + bt * BT) * HP;
#pragma unroll
      for (int K = 0; K < 10; ++K)
#pragma unroll
        for (int j = 0; j < 2; j++)
          bfx[K][j] = *(const half8*)(xb + (j * 16 + lr) * HP + K * 32 + kq);
#pragma unroll
      for (int K = 10; K < 20; ++K)
#pragma unroll
        for (int j = 0; j < 2; j++)
          bfx[K][j] =
              *(const half8*)(hcur + (j * 16 + lr) * HROW + (K - 10) * 32 + kq);
    }

    for (int m = 0; m < 5; ++m) {
      f32x4 acc[4][2];
#pragma unroll
      for (int i = 0; i < 4; i++)
#pragma unroll
        for (int j = 0; j < 2; j++) acc[i][j] = (f32x4){0.f, 0.f, 0.f, 0.f};

#pragma unroll
      for (int kt = 0; kt < 20; ++kt) {
        // stage slab g+2 (g = m*20+kt); wraps to next timestep's slabs 0/1
        // (weights are t-invariant, so the pipeline free-runs across t).
        {
          int m2, kt2;
          if (kt < 18) { m2 = m; kt2 = kt + 2; }
          else         { m2 = (m == 4) ? 0 : m + 1; kt2 = kt - 18; }
          const int buf2 = (m * 20 + kt + 2) & 3;
          STAGE(m2, kt2, buf2)
        }
        // wait for slab g (8 newest vmem ops = the 2 in-flight slabs; any
        // interleaved x-loads/stores only cause a harmless over-wait)
        asm volatile("s_waitcnt vmcnt(8)" ::: "memory");
        __builtin_amdgcn_s_barrier();

        const int buf = (m * 20 + kt) & 3;
        const f16* Af = (const f16*)(smem + A_OFF + buf * SLABB);
        half8 af[4];
#pragma unroll
        for (int i = 0; i < 4; i++) af[i] = *(const half8*)(Af + abase + i * 512);
#pragma unroll
        for (int i = 0; i < 4; i++)
#pragma unroll
          for (int j = 0; j < 2; j++)
            acc[i][j] = __builtin_amdgcn_mfma_f32_16x16x32_f16(
                af[i], bfx[kt][j], acc[i][j], 0, 0, 0);
      }

      // ---- gate epilogue for this chunk: c (LDS), h_new -> hnxt ----
#pragma unroll
      for (int i = 0; i < 4; i++) {
        const int jh = m * 64 + wave * 16 + i * 4 + lq;  // 0..319
        const float4 b4 = *(const float4*)&bl[4 * jh];
#pragma unroll
        for (int j = 0; j < 2; j++) {
          const int b = j * 16 + lr;  // 0..31
          float* cp = &cls[jh * 33 + b];
          const float co = *cp;
          const float zi = acc[i][j][0] + b4.x;
          const float zf = acc[i][j][1] + b4.y;
          const float zg = acc[i][j][2] + b4.z;
          const float zo = acc[i][j][3] + b4.w;
          const float cn = sigmoid_(zf) * co + sigmoid_(zi) * tanh_fast(zg);
          *cp = cn;  // pad rows (jh>=300): zero weights/bias -> stays 0
          hnxt[b * HROW + jh] = (f16)(sigmoid_(zo) * tanh_fast(cn));
        }
      }
    }

    // t-end: make hnxt visible to all waves WITHOUT draining the DMA queue
    asm volatile("s_waitcnt lgkmcnt(0)" ::: "memory");
    __builtin_amdgcn_s_barrier();

    // ---- hs write-out: rows [b][304] contiguous from hnxt row b ----
    for (int idx = tid; idx < 32 * 38; idx += 256) {
      const int b = idx / 38, ch = idx % 38;  // 38 half8 chunks = 304 f16
      f16* dst = hs + ((size_t)d * B_ + bt * BT + b) * SB2 + t * TR;
      *(half8*)(dst + ch * 8) = *(const half8*)(hnxt + b * HROW + ch * 8);
    }
  }
#undef STAGE
}

// ---------------------------------------------------------------------------
// attn1: alpha[b][t] = softmax_t( sum_h tanh(hs0+hs1) * conv_w[h] ).
// Pure stream over hs; half4 loads (rows are 304-wide, zero-padded).
// ---------------------------------------------------------------------------
__global__ __launch_bounds__(256) void attn1(const f16* __restrict__ hs,
                                             const float* __restrict__ conv_w,
                                             float* __restrict__ alpha_g) {
  __shared__ float cw[TR];
  __shared__ float red[48];
  const int b = blockIdx.x, tid = threadIdx.x;
  const int wave = tid >> 6, lane = tid & 63;
  for (int k = tid; k < TR; k += 256) cw[k] = (k < H_) ? conv_w[k] : 0.f;
  __syncthreads();

  const half4* s0 = (const half4*)(hs + (size_t)b * SB2);
  const half4* s1 = (const half4*)(hs + (size_t)(B_ + b) * SB2);
  for (int t = wave; t < T_; t += 4) {
    const int base = t * (TR / 4);
    float p = 0.f;
    {
      half4 a = s0[base + lane], cc = s1[base + lane];
#pragma unroll
      for (int r = 0; r < 4; r++)
        p += tanh_fast((float)a[r] + (float)cc[r]) * cw[lane * 4 + r];
    }
    if (lane < 12) {
      half4 a = s0[base + 64 + lane], cc = s1[base + 64 + lane];
#pragma unroll
      for (int r = 0; r < 4; r++)
        p += tanh_fast((float)a[r] + (float)cc[r]) * cw[256 + lane * 4 + r];
    }
#pragma unroll
    for (int o = 32; o; o >>= 1) p += __shfl_down(p, o);
    if (lane == 0) red[t] = p;
  }
  __syncthreads();
  if (tid < 64) {
    float a = (tid < T_) ? red[tid] : -1e30f;
    float mx = a;
#pragma unroll
    for (int o = 32; o; o >>= 1) mx = fmaxf(mx, __shfl_xor(mx, o));
    float e = (tid < T_) ? __expf(a - mx) : 0.f;
    float s = e;
#pragma unroll
    for (int o = 32; o; o >>= 1) s += __shfl_xor(s, o);
    if (tid < T_) alpha_g[(size_t)b * 44 + tid] = e / s;
  }
}

// ---------------------------------------------------------------------------
// attn2: r[b][h] = sum_t hsum*alpha; hstar = tanh(r); logits; softmax.
// Thread-per-h accumulation, coalesced streaming.
// ---------------------------------------------------------------------------
__global__ __launch_bounds__(256) void attn2(const f16* __restrict__ hs,
                                             const float* __restrict__ alpha_g,
                                             const float* __restrict__ fc_w,
                                             const float* __restrict__ fc_b,
                                             float* __restrict__ out) {
  __shared__ float al[T_];
  __shared__ float hstar[TR];
  __shared__ float lg[NC_];
  const int b = blockIdx.x, tid = threadIdx.x;
  if (tid < T_) al[tid] = alpha_g[(size_t)b * 44 + tid];
  __syncthreads();

  const f16* s0 = hs + (size_t)b * SB2;
  const f16* s1 = hs + (size_t)(B_ + b) * SB2;
  float r0 = 0.f, r1 = 0.f;
  for (int t = 0; t < T_; t++) {
    const float a = al[t];
    r0 += ((float)s0[t * TR + tid] + (float)s1[t * TR + tid]) * a;
    if (tid < 48)
      r1 += ((float)s0[t * TR + 256 + tid] + (float)s1[t * TR + 256 + tid]) * a;
  }
  hstar[tid] = tanh_fast(r0);
  if (tid < 48) hstar[256 + tid] = tanh_fast(r1);
  __syncthreads();

  const int wave = tid >> 6, lane = tid & 63;
  for (int cls = wave; cls < NC_; cls += 4) {
    float p = 0.f;
    for (int k = lane; k < H_; k += 64) p += hstar[k] * fc_w[(size_t)cls * H_ + k];
#pragma unroll
    for (int o = 32; o; o >>= 1) p += __shfl_down(p, o);
    if (lane == 0) lg[cls] = p + fc_b[cls];
  }
  __syncthreads();
  if (tid < 64) {
    float a0 = (tid < 40) ? lg[tid] : -1e30f;
    float a1 = (tid < 40) ? lg[tid + 40] : -1e30f;
    float mx = fmaxf(a0, a1);
#pragma unroll
    for (int o = 32; o; o >>= 1) mx = fmaxf(mx, __shfl_xor(mx, o));
    float e0 = (tid < 40) ? __expf(a0 - mx) : 0.f;
    float e1 = (tid < 40) ? __expf(a1 - mx) : 0.f;
    float s = e0 + e1;
#pragma unroll
    for (int o = 32; o; o >>= 1) s += __shfl_xor(s, o);
    if (tid < 40) {
      out[(size_t)b * NC_ + tid] = e0 / s;
      out[(size_t)b * NC_ + tid + 40] = e1 / s;
    }
  }
}

// ---------------------------------------------------------------------------
extern "C" void kernel_launch(void* const* d_in, const int* in_sizes, int n_in,
                              void* d_out, int out_size, void* d_ws, size_t ws_size,
                              hipStream_t stream) {
  const float* x      = (const float*)d_in[0];
  const float* w_ih   = (const float*)d_in[1];
  const float* w_hh   = (const float*)d_in[2];
  const float* b_ih   = (const float*)d_in[3];
  const float* b_hh   = (const float*)d_in[4];
  const float* conv_w = (const float*)d_in[5];
  const float* fc_w   = (const float*)d_in[6];
  const float* fc_b   = (const float*)d_in[7];
  float* out = (float*)d_out;

  // Workspace carve (~331 MB)
  char* p = (char*)d_ws;
  f16* Wcat = (f16*)p;  p += (size_t)NDD * KC * sizeof(f16);        // 3.3 MB
  float* bias = (float*)p; p += (size_t)NDD * sizeof(float);
  p = (char*)(((uintptr_t)p + 255) & ~(uintptr_t)255);
  f16* xT = (f16*)p;    p += (size_t)T_ * B_ * HP * sizeof(f16);    // 112.7 MB
  f16* hs = (f16*)p;    p += (size_t)2 * B_ * SB2 * sizeof(f16);    // 214.2 MB
  float* alpha_g = (float*)p; p += (size_t)B_ * 44 * sizeof(float); // 0.72 MB

  prep_weights<<<(NDD * KC + 255) / 256, 256, 0, stream>>>(
      w_ih, w_hh, b_ih, b_hh, Wcat, bias);
  prep_xT<<<dim3(B_, 5), 256, 0, stream>>>(x, xT);

  lstm_all<<<256, 256, LDS_TOTAL, stream>>>(xT, Wcat, bias, hs);

  attn1<<<B_, 256, 0, stream>>>(hs, conv_w, alpha_g);
  attn2<<<B_, 256, 0, stream>>>(hs, alpha_g, fc_w, fc_b, out);
}